// Round 1
// baseline (401.080 us; speedup 1.0000x reference)
//
#include <hip/hip_runtime.h>
#include <hip/hip_bf16.h>

#define T_TOK 4096
#define DDIM  1024
#define HDIM  2048
#define NEXP  8

#define BM 128
#define BN 128
#define BK 64
#define LDK 72   // 64 + 8 bf16 pad -> 144B row stride, breaks bank conflicts, keeps 16B align

typedef __attribute__((ext_vector_type(4))) float f32x4;
typedef __attribute__((ext_vector_type(8))) short s16x8;
typedef __hip_bfloat16 bf16;

// ---------------- router: fp64-accumulated logits, top-2 + softmax ----------------
__global__ void router_kernel(const float* __restrict__ x, const float* __restrict__ rw,
                              int* __restrict__ r_e, float* __restrict__ r_w) {
    int wave = threadIdx.x >> 6, lane = threadIdx.x & 63;
    int t = blockIdx.x * 4 + wave;
    if (t >= T_TOK) return;
    const float* xr = x + (size_t)t * DDIM;
    double acc[NEXP];
#pragma unroll
    for (int e = 0; e < NEXP; ++e) acc[e] = 0.0;
    for (int d = lane; d < DDIM; d += 64) {
        float xv = xr[d];
        const float* rwr = rw + (size_t)d * NEXP;
#pragma unroll
        for (int e = 0; e < NEXP; ++e) acc[e] += (double)xv * (double)rwr[e];
    }
#pragma unroll
    for (int e = 0; e < NEXP; ++e) {
#pragma unroll
        for (int off = 32; off > 0; off >>= 1) acc[e] += __shfl_down(acc[e], off);
    }
    if (lane == 0) {
        int i0 = 0; double v0 = acc[0];
#pragma unroll
        for (int e = 1; e < NEXP; ++e) if (acc[e] > v0) { v0 = acc[e]; i0 = e; }
        int i1 = -1; double v1 = -1e300;
#pragma unroll
        for (int e = 0; e < NEXP; ++e) { if (e == i0) continue; if (acc[e] > v1) { v1 = acc[e]; i1 = e; } }
        float w0 = 1.0f / (1.0f + expf((float)(v1 - v0)));
        float w1 = 1.0f - w0;
        r_e[2*t]   = i0; r_e[2*t+1] = i1;
        r_w[2*t]   = w0; r_w[2*t+1] = w1;
    }
}

// ---------------- binning ----------------
__global__ void count_kernel(const int* __restrict__ r_e, int* __restrict__ cnt) {
    int i = blockIdx.x * blockDim.x + threadIdx.x;
    if (i < 2 * T_TOK) atomicAdd(&cnt[r_e[i]], 1);
}
__global__ void scan_kernel(const int* __restrict__ cnt, int* __restrict__ offs) {
    if (threadIdx.x == 0) {
        int s = 0;
        for (int e = 0; e < NEXP; ++e) { offs[e] = s; s += cnt[e]; }
        offs[NEXP] = s;
    }
}
__global__ void fill_kernel(const int* __restrict__ r_e, const int* __restrict__ offs,
                            int* __restrict__ cnt2, int* __restrict__ list, int* __restrict__ tokslot) {
    int i = blockIdx.x * blockDim.x + threadIdx.x;  // i = 2*t + r
    if (i < 2 * T_TOK) {
        int e = r_e[i];
        int pos = atomicAdd(&cnt2[e], 1);
        int slot = offs[e] + pos;
        list[slot] = i >> 1;
        tokslot[i] = slot;
    }
}

// ---------------- transpose + fp32->bf16 cast, per-expert matrices ----------------
// in: [R][C] fp32, out: [C][R] bf16 (E matrices along blockIdx.z). R,C multiples of 64.
__global__ void transpose_cast_kernel(const float* __restrict__ in, bf16* __restrict__ out,
                                      int R, int C) {
    __shared__ bf16 tile[64][66];
    size_t mat = (size_t)blockIdx.z * R * C;
    const float* inp = in + mat;
    bf16* outp = out + mat;
    int r0 = blockIdx.x * 64, c0 = blockIdx.y * 64;
    int tx = threadIdx.x & 63, ty = threadIdx.x >> 6;
#pragma unroll
    for (int i = ty; i < 64; i += 4)
        tile[i][tx] = __float2bfloat16(inp[(size_t)(r0 + i) * C + (c0 + tx)]);
    __syncthreads();
#pragma unroll
    for (int j = ty; j < 64; j += 4)
        outp[(size_t)(c0 + j) * R + (r0 + tx)] = tile[tx][j];
}

// ---------------- x -> bf16 cast ----------------
__global__ void cast_x_kernel(const float* __restrict__ x, bf16* __restrict__ xb) {
    size_t i = (size_t)(blockIdx.x * blockDim.x + threadIdx.x) * 4;
    float4 v = *reinterpret_cast<const float4*>(x + i);
    union { ushort4 u; bf16 h[4]; } o;
    o.h[0] = __float2bfloat16(v.x);
    o.h[1] = __float2bfloat16(v.y);
    o.h[2] = __float2bfloat16(v.z);
    o.h[3] = __float2bfloat16(v.w);
    *reinterpret_cast<ushort4*>(xb + i) = o.u;
}

// ---------------- pass 1: gate + up GEMM, fused silu, per-expert grouped rows ----------------
// A = gathered xb rows [ne, D]; Bg/Bu = wgT/wuT [H][D] (bf16, "B^T" layout); out hbuf bf16 [slot][H]
__global__ __launch_bounds__(256, 2)
void gateup_kernel(const bf16* __restrict__ xb, const bf16* __restrict__ wgT,
                   const bf16* __restrict__ wuT, const int* __restrict__ offs,
                   const int* __restrict__ list, bf16* __restrict__ hbuf) {
    int e = blockIdx.z;
    int base = offs[e];
    int ne = offs[e + 1] - base;
    int m0 = blockIdx.y * BM;
    if (m0 >= ne) return;
    int n0 = blockIdx.x * BN;  // h-tile

    __shared__ alignas(16) bf16 Asm[BM][LDK];
    __shared__ alignas(16) bf16 Bgs[BN][LDK];
    __shared__ alignas(16) bf16 Bus[BN][LDK];
    __shared__ int toks[BM];

    int tid = threadIdx.x;
    if (tid < BM) {
        int r = m0 + tid;
        toks[tid] = (r < ne) ? list[base + r] : -1;
    }
    __syncthreads();

    int lane = tid & 63, wid = tid >> 6;
    int wr = (wid >> 1) * 64, wc = (wid & 1) * 64;
    f32x4 zero4 = {0.f, 0.f, 0.f, 0.f};
    f32x4 accg[4][4], accu[4][4];
#pragma unroll
    for (int mi = 0; mi < 4; ++mi)
#pragma unroll
        for (int ni = 0; ni < 4; ++ni) { accg[mi][ni] = zero4; accu[mi][ni] = zero4; }

    const bf16* wgp = wgT + ((size_t)e * HDIM + n0) * DDIM;
    const bf16* wup = wuT + ((size_t)e * HDIM + n0) * DDIM;

    for (int k0 = 0; k0 < DDIM; k0 += BK) {
        // stage A (gathered, guarded) + Bg + Bu : 16B chunks
#pragma unroll
        for (int i = 0; i < 4; ++i) {
            int c = tid + i * 256;
            int row = c >> 3, kc = (c & 7) * 8;
            int tok = toks[row];
            int4 av = {};
            if (tok >= 0) av = *reinterpret_cast<const int4*>(xb + (size_t)tok * DDIM + k0 + kc);
            *reinterpret_cast<int4*>(&Asm[row][kc]) = av;
            *reinterpret_cast<int4*>(&Bgs[row][kc]) =
                *reinterpret_cast<const int4*>(wgp + (size_t)row * DDIM + k0 + kc);
            *reinterpret_cast<int4*>(&Bus[row][kc]) =
                *reinterpret_cast<const int4*>(wup + (size_t)row * DDIM + k0 + kc);
        }
        __syncthreads();
#pragma unroll
        for (int kk = 0; kk < BK; kk += 32) {
            int ko = kk + 8 * (lane >> 4);
            int rl = lane & 15;
            s16x8 a[4], bg[4], bu[4];
#pragma unroll
            for (int mi = 0; mi < 4; ++mi)
                a[mi] = *reinterpret_cast<const s16x8*>(&Asm[wr + mi * 16 + rl][ko]);
#pragma unroll
            for (int ni = 0; ni < 4; ++ni) {
                bg[ni] = *reinterpret_cast<const s16x8*>(&Bgs[wc + ni * 16 + rl][ko]);
                bu[ni] = *reinterpret_cast<const s16x8*>(&Bus[wc + ni * 16 + rl][ko]);
            }
#pragma unroll
            for (int mi = 0; mi < 4; ++mi)
#pragma unroll
                for (int ni = 0; ni < 4; ++ni) {
                    accg[mi][ni] = __builtin_amdgcn_mfma_f32_16x16x32_bf16(a[mi], bg[ni], accg[mi][ni], 0, 0, 0);
                    accu[mi][ni] = __builtin_amdgcn_mfma_f32_16x16x32_bf16(a[mi], bu[ni], accu[mi][ni], 0, 0, 0);
                }
        }
        __syncthreads();
    }

    // epilogue: h = silu(g)*u -> hbuf (bf16). C/D: row=(lane>>4)*4+reg, col=lane&15
    int rbase = (lane >> 4) * 4, cbase = lane & 15;
#pragma unroll
    for (int mi = 0; mi < 4; ++mi) {
#pragma unroll
        for (int r = 0; r < 4; ++r) {
            int row = m0 + wr + mi * 16 + rbase + r;
            if (row < ne) {
                size_t orow = (size_t)(base + row) * HDIM + n0 + wc + cbase;
#pragma unroll
                for (int ni = 0; ni < 4; ++ni) {
                    float g = accg[mi][ni][r], u = accu[mi][ni][r];
                    float h = (g / (1.0f + expf(-g))) * u;
                    hbuf[orow + ni * 16] = __float2bfloat16(h);
                }
            }
        }
    }
}

// ---------------- pass 2: down GEMM -> obuf fp32 per slot ----------------
__global__ __launch_bounds__(256, 2)
void down_kernel(const bf16* __restrict__ hbuf, const bf16* __restrict__ wdT,
                 const int* __restrict__ offs, float* __restrict__ obuf) {
    int e = blockIdx.z;
    int base = offs[e];
    int ne = offs[e + 1] - base;
    int m0 = blockIdx.y * BM;
    if (m0 >= ne) return;
    int n0 = blockIdx.x * BN;  // d-tile

    __shared__ alignas(16) bf16 Asm[BM][LDK];
    __shared__ alignas(16) bf16 Bsm[BN][LDK];

    int tid = threadIdx.x, lane = tid & 63, wid = tid >> 6;
    int wr = (wid >> 1) * 64, wc = (wid & 1) * 64;
    f32x4 zero4 = {0.f, 0.f, 0.f, 0.f};
    f32x4 acc[4][4];
#pragma unroll
    for (int mi = 0; mi < 4; ++mi)
#pragma unroll
        for (int ni = 0; ni < 4; ++ni) acc[mi][ni] = zero4;

    const bf16* wdp = wdT + ((size_t)e * DDIM + n0) * HDIM;

    for (int k0 = 0; k0 < HDIM; k0 += BK) {
#pragma unroll
        for (int i = 0; i < 4; ++i) {
            int c = tid + i * 256;
            int row = c >> 3, kc = (c & 7) * 8;
            int r = m0 + row;
            int4 av = {};
            if (r < ne) av = *reinterpret_cast<const int4*>(hbuf + (size_t)(base + r) * HDIM + k0 + kc);
            *reinterpret_cast<int4*>(&Asm[row][kc]) = av;
            *reinterpret_cast<int4*>(&Bsm[row][kc]) =
                *reinterpret_cast<const int4*>(wdp + (size_t)row * HDIM + k0 + kc);
        }
        __syncthreads();
#pragma unroll
        for (int kk = 0; kk < BK; kk += 32) {
            int ko = kk + 8 * (lane >> 4);
            int rl = lane & 15;
            s16x8 a[4], b[4];
#pragma unroll
            for (int mi = 0; mi < 4; ++mi)
                a[mi] = *reinterpret_cast<const s16x8*>(&Asm[wr + mi * 16 + rl][ko]);
#pragma unroll
            for (int ni = 0; ni < 4; ++ni)
                b[ni] = *reinterpret_cast<const s16x8*>(&Bsm[wc + ni * 16 + rl][ko]);
#pragma unroll
            for (int mi = 0; mi < 4; ++mi)
#pragma unroll
                for (int ni = 0; ni < 4; ++ni)
                    acc[mi][ni] = __builtin_amdgcn_mfma_f32_16x16x32_bf16(a[mi], b[ni], acc[mi][ni], 0, 0, 0);
        }
        __syncthreads();
    }

    int rbase = (lane >> 4) * 4, cbase = lane & 15;
#pragma unroll
    for (int mi = 0; mi < 4; ++mi) {
#pragma unroll
        for (int r = 0; r < 4; ++r) {
            int row = m0 + wr + mi * 16 + rbase + r;
            if (row < ne) {
                size_t orow = (size_t)(base + row) * DDIM + n0 + wc + cbase;
#pragma unroll
                for (int ni = 0; ni < 4; ++ni)
                    obuf[orow + ni * 16] = acc[mi][ni][r];
            }
        }
    }
}

// ---------------- combine: y[t] = w0*obuf[slot0] + w1*obuf[slot1] (fixed order -> deterministic) ----
__global__ void combine_kernel(const float* __restrict__ obuf, const int* __restrict__ tokslot,
                               const float* __restrict__ r_w, float* __restrict__ y) {
    int i = blockIdx.x * blockDim.x + threadIdx.x;
    int t = i >> 8;            // 256 float4 per token row (D=1024)
    int d4 = (i & 255) * 4;
    float w0 = r_w[2 * t], w1 = r_w[2 * t + 1];
    int s0 = tokslot[2 * t], s1 = tokslot[2 * t + 1];
    float4 a = *reinterpret_cast<const float4*>(obuf + (size_t)s0 * DDIM + d4);
    float4 b = *reinterpret_cast<const float4*>(obuf + (size_t)s1 * DDIM + d4);
    float4 o;
    o.x = w0 * a.x + w1 * b.x;
    o.y = w0 * a.y + w1 * b.y;
    o.z = w0 * a.z + w1 * b.z;
    o.w = w0 * a.w + w1 * b.w;
    *reinterpret_cast<float4*>(y + (size_t)t * DDIM + d4) = o;
}

extern "C" void kernel_launch(void* const* d_in, const int* in_sizes, int n_in,
                              void* d_out, int out_size, void* d_ws, size_t ws_size,
                              hipStream_t stream) {
    const float* x  = (const float*)d_in[0];
    const float* rw = (const float*)d_in[1];
    const float* wg = (const float*)d_in[2];
    const float* wu = (const float*)d_in[3];
    const float* wd = (const float*)d_in[4];
    float* y = (float*)d_out;

    char* ws = (char*)d_ws;
    int*   r_e     = (int*)  (ws + 0);          // 2T ints   = 32768 B
    float* r_w     = (float*)(ws + 32768);      // 2T floats = 32768 B
    int*   cnt     = (int*)  (ws + 65536);      // 8 ints
    int*   cnt2    = (int*)  (ws + 65568);      // 8 ints
    int*   offs    = (int*)  (ws + 65600);      // 9 ints
    int*   list    = (int*)  (ws + 65664);      // 2T ints
    int*   tokslot = (int*)  (ws + 98432);      // 2T ints
    bf16*  xb      = (bf16*) (ws + (1u << 20));             // 8,388,608 B
    bf16*  wgT     = (bf16*) (ws + 9437184ull);             // 33,554,432 B
    bf16*  wuT     = (bf16*) (ws + 42991616ull);            // 33,554,432 B
    bf16*  wdT     = (bf16*) (ws + 76546048ull);            // 33,554,432 B
    bf16*  hbuf    = (bf16*) (ws + 110100480ull);           // 33,554,432 B
    float* obuf    = (float*)(ws + 143654912ull);           // 33,554,432 B  (end ~177.2 MB)

    // weight transposes + casts
    transpose_cast_kernel<<<dim3(DDIM / 64, HDIM / 64, NEXP), 256, 0, stream>>>(wg, wgT, DDIM, HDIM);
    transpose_cast_kernel<<<dim3(DDIM / 64, HDIM / 64, NEXP), 256, 0, stream>>>(wu, wuT, DDIM, HDIM);
    transpose_cast_kernel<<<dim3(HDIM / 64, DDIM / 64, NEXP), 256, 0, stream>>>(wd, wdT, HDIM, DDIM);
    cast_x_kernel<<<dim3(T_TOK * DDIM / 4 / 256), 256, 0, stream>>>(x, xb);

    // routing
    router_kernel<<<dim3(T_TOK / 4), 256, 0, stream>>>(x, rw, r_e, r_w);
    hipMemsetAsync(ws + 65536, 0, 64, stream);  // cnt + cnt2
    count_kernel<<<dim3(2 * T_TOK / 256), 256, 0, stream>>>(r_e, cnt);
    scan_kernel<<<dim3(1), 64, 0, stream>>>(cnt, offs);
    fill_kernel<<<dim3(2 * T_TOK / 256), 256, 0, stream>>>(r_e, offs, cnt2, list, tokslot);

    // expert GEMMs (grouped, worst-case grid with early-exit)
    gateup_kernel<<<dim3(HDIM / BN, T_TOK / BM, NEXP), 256, 0, stream>>>(xb, wgT, wuT, offs, list, hbuf);
    down_kernel<<<dim3(DDIM / BN, T_TOK / BM, NEXP), 256, 0, stream>>>(hbuf, wdT, offs, obuf);

    // combine
    combine_kernel<<<dim3(T_TOK * DDIM / 4 / 256), 256, 0, stream>>>(obuf, tokslot, r_w, y);
}

// Round 2
// 350.201 us; speedup vs baseline: 1.1453x; 1.1453x over previous
//
#include <hip/hip_runtime.h>
#include <hip/hip_bf16.h>

#define T_TOK 4096
#define DDIM  1024
#define HDIM  2048
#define NEXP  8

#define BM 128
#define BN 128
#define BK 64

typedef __attribute__((ext_vector_type(4))) float f32x4;
typedef __attribute__((ext_vector_type(8))) short s16x8;
typedef __hip_bfloat16 bf16;

typedef const void __attribute__((address_space(1))) gvoid;
typedef void __attribute__((address_space(3))) svoid;

__device__ __forceinline__ void gload16(const void* g, void* l) {
    // async global->LDS, 16B per lane; LDS dest = wave-uniform base + lane*16
    __builtin_amdgcn_global_load_lds((gvoid*)g, (svoid*)l, 16, 0, 0);
}

// ---------------- router: fp64-accumulated logits, top-2 + softmax ----------------
__global__ void router_kernel(const float* __restrict__ x, const float* __restrict__ rw,
                              int* __restrict__ r_e, float* __restrict__ r_w) {
    int wave = threadIdx.x >> 6, lane = threadIdx.x & 63;
    int t = blockIdx.x * 4 + wave;
    if (t >= T_TOK) return;
    const float* xr = x + (size_t)t * DDIM;
    double acc[NEXP];
#pragma unroll
    for (int e = 0; e < NEXP; ++e) acc[e] = 0.0;
    for (int d = lane; d < DDIM; d += 64) {
        float xv = xr[d];
        const float* rwr = rw + (size_t)d * NEXP;
#pragma unroll
        for (int e = 0; e < NEXP; ++e) acc[e] += (double)xv * (double)rwr[e];
    }
#pragma unroll
    for (int e = 0; e < NEXP; ++e) {
#pragma unroll
        for (int off = 32; off > 0; off >>= 1) acc[e] += __shfl_down(acc[e], off);
    }
    if (lane == 0) {
        int i0 = 0; double v0 = acc[0];
#pragma unroll
        for (int e = 1; e < NEXP; ++e) if (acc[e] > v0) { v0 = acc[e]; i0 = e; }
        int i1 = -1; double v1 = -1e300;
#pragma unroll
        for (int e = 0; e < NEXP; ++e) { if (e == i0) continue; if (acc[e] > v1) { v1 = acc[e]; i1 = e; } }
        float w0 = 1.0f / (1.0f + expf((float)(v1 - v0)));
        float w1 = 1.0f - w0;
        r_e[2*t]   = i0; r_e[2*t+1] = i1;
        r_w[2*t]   = w0; r_w[2*t+1] = w1;
    }
}

// ---------------- binning ----------------
__global__ void count_kernel(const int* __restrict__ r_e, int* __restrict__ cnt) {
    int i = blockIdx.x * blockDim.x + threadIdx.x;
    if (i < 2 * T_TOK) atomicAdd(&cnt[r_e[i]], 1);
}
__global__ void scan_kernel(const int* __restrict__ cnt, int* __restrict__ offs) {
    if (threadIdx.x == 0) {
        int s = 0;
        for (int e = 0; e < NEXP; ++e) { offs[e] = s; s += cnt[e]; }
        offs[NEXP] = s;
    }
}
__global__ void fill_kernel(const int* __restrict__ r_e, const int* __restrict__ offs,
                            int* __restrict__ cnt2, int* __restrict__ list, int* __restrict__ tokslot) {
    int i = blockIdx.x * blockDim.x + threadIdx.x;  // i = 2*t + r
    if (i < 2 * T_TOK) {
        int e = r_e[i];
        int pos = atomicAdd(&cnt2[e], 1);
        int slot = offs[e] + pos;
        list[slot] = i >> 1;
        tokslot[i] = slot;
    }
}

// ---------------- transpose + fp32->bf16 cast, per-expert matrices ----------------
__global__ void transpose_cast_kernel(const float* __restrict__ in, bf16* __restrict__ out,
                                      int R, int C) {
    __shared__ bf16 tile[64][66];
    size_t mat = (size_t)blockIdx.z * R * C;
    const float* inp = in + mat;
    bf16* outp = out + mat;
    int r0 = blockIdx.x * 64, c0 = blockIdx.y * 64;
    int tx = threadIdx.x & 63, ty = threadIdx.x >> 6;
#pragma unroll
    for (int i = ty; i < 64; i += 4)
        tile[i][tx] = __float2bfloat16(inp[(size_t)(r0 + i) * C + (c0 + tx)]);
    __syncthreads();
#pragma unroll
    for (int j = ty; j < 64; j += 4)
        outp[(size_t)(c0 + j) * R + (r0 + tx)] = tile[tx][j];
}

// ---------------- x -> bf16 cast ----------------
__global__ void cast_x_kernel(const float* __restrict__ x, bf16* __restrict__ xb) {
    size_t i = (size_t)(blockIdx.x * blockDim.x + threadIdx.x) * 4;
    float4 v = *reinterpret_cast<const float4*>(x + i);
    union { ushort4 u; bf16 h[4]; } o;
    o.h[0] = __float2bfloat16(v.x);
    o.h[1] = __float2bfloat16(v.y);
    o.h[2] = __float2bfloat16(v.z);
    o.h[3] = __float2bfloat16(v.w);
    *reinterpret_cast<ushort4*>(xb + i) = o.u;
}

// ---------------- pass 1: gate + up GEMM (m97 structure: global_load_lds, linear LDS) -------
__global__ __launch_bounds__(256, 2)
void gateup_kernel(const bf16* __restrict__ xb, const bf16* __restrict__ wgT,
                   const bf16* __restrict__ wuT, const int* __restrict__ offs,
                   const int* __restrict__ list, bf16* __restrict__ hbuf) {
    int e = blockIdx.z;
    int base = offs[e];
    int ne = offs[e + 1] - base;
    int m0 = blockIdx.y * BM;
    if (m0 >= ne) return;
    int n0 = blockIdx.x * BN;  // h-tile

    __shared__ bf16 Asm[BM][BK];   // 16 KB, linear (global_load_lds requires contiguous dest)
    __shared__ bf16 Bgs[BN][BK];
    __shared__ bf16 Bus[BN][BK];

    int tid = threadIdx.x, lane = tid & 63, wid = tid >> 6;
    int sub  = lane >> 3;          // row within this lane's 8-row chunk
    int koff = (lane & 7) * 8;     // element offset in row (16B granule)

    // Per-thread source pointers for 4 staging chunks per buffer.
    // A rows are gathered token rows; out-of-range rows clamp to a valid slot
    // (finite garbage, never stored by the guarded epilogue).
    const bf16* asrc[4]; const bf16* gsrc[4]; const bf16* usrc[4];
    bf16* adst[4]; bf16* gdst[4]; bf16* udst[4];
    const bf16* wgp = wgT + ((size_t)e * HDIM + n0) * DDIM;
    const bf16* wup = wuT + ((size_t)e * HDIM + n0) * DDIM;
#pragma unroll
    for (int i = 0; i < 4; ++i) {
        int c = wid * 4 + i;       // chunk 0..15, covers rows 8c..8c+7
        int row = c * 8 + sub;
        int r = m0 + row; if (r > ne - 1) r = ne - 1;
        int tok = list[base + r];
        asrc[i] = xb + (size_t)tok * DDIM + koff;
        gsrc[i] = wgp + (size_t)row * DDIM + koff;
        usrc[i] = wup + (size_t)row * DDIM + koff;
        adst[i] = &Asm[c * 8][0];  // wave-uniform
        gdst[i] = &Bgs[c * 8][0];
        udst[i] = &Bus[c * 8][0];
    }

    int wr = (wid >> 1) * 64, wc = (wid & 1) * 64;
    f32x4 zero4 = {0.f, 0.f, 0.f, 0.f};
    f32x4 accg[4][4], accu[4][4];
#pragma unroll
    for (int mi = 0; mi < 4; ++mi)
#pragma unroll
        for (int ni = 0; ni < 4; ++ni) { accg[mi][ni] = zero4; accu[mi][ni] = zero4; }

    for (int k0 = 0; k0 < DDIM; k0 += BK) {
#pragma unroll
        for (int i = 0; i < 4; ++i) gload16(asrc[i] + k0, adst[i]);
#pragma unroll
        for (int i = 0; i < 4; ++i) gload16(gsrc[i] + k0, gdst[i]);
#pragma unroll
        for (int i = 0; i < 4; ++i) gload16(usrc[i] + k0, udst[i]);
        __syncthreads();           // drains vmcnt -> LDS valid
#pragma unroll
        for (int kk = 0; kk < BK; kk += 32) {
            int ko = kk + 8 * (lane >> 4);
            int rl = lane & 15;
            s16x8 a[4], bg[4], bu[4];
#pragma unroll
            for (int mi = 0; mi < 4; ++mi)
                a[mi] = *reinterpret_cast<const s16x8*>(&Asm[wr + mi * 16 + rl][ko]);
#pragma unroll
            for (int ni = 0; ni < 4; ++ni) {
                bg[ni] = *reinterpret_cast<const s16x8*>(&Bgs[wc + ni * 16 + rl][ko]);
                bu[ni] = *reinterpret_cast<const s16x8*>(&Bus[wc + ni * 16 + rl][ko]);
            }
#pragma unroll
            for (int mi = 0; mi < 4; ++mi)
#pragma unroll
                for (int ni = 0; ni < 4; ++ni) {
                    accg[mi][ni] = __builtin_amdgcn_mfma_f32_16x16x32_bf16(a[mi], bg[ni], accg[mi][ni], 0, 0, 0);
                    accu[mi][ni] = __builtin_amdgcn_mfma_f32_16x16x32_bf16(a[mi], bu[ni], accu[mi][ni], 0, 0, 0);
                }
        }
        __syncthreads();
    }

    // epilogue: h = silu(g)*u -> hbuf (bf16). C/D: row=(lane>>4)*4+reg, col=lane&15
    int rbase = (lane >> 4) * 4, cbase = lane & 15;
#pragma unroll
    for (int mi = 0; mi < 4; ++mi) {
#pragma unroll
        for (int r = 0; r < 4; ++r) {
            int row = m0 + wr + mi * 16 + rbase + r;
            if (row < ne) {
                size_t orow = (size_t)(base + row) * HDIM + n0 + wc + cbase;
#pragma unroll
                for (int ni = 0; ni < 4; ++ni) {
                    float g = accg[mi][ni][r], u = accu[mi][ni][r];
                    float h = (g / (1.0f + expf(-g))) * u;
                    hbuf[orow + ni * 16] = __float2bfloat16(h);
                }
            }
        }
    }
}

// ---------------- pass 2: down GEMM -> obuf fp32 per slot ----------------
__global__ __launch_bounds__(256, 2)
void down_kernel(const bf16* __restrict__ hbuf, const bf16* __restrict__ wdT,
                 const int* __restrict__ offs, float* __restrict__ obuf) {
    int e = blockIdx.z;
    int base = offs[e];
    int ne = offs[e + 1] - base;
    int m0 = blockIdx.y * BM;
    if (m0 >= ne) return;
    int n0 = blockIdx.x * BN;  // d-tile

    __shared__ bf16 Asm[BM][BK];
    __shared__ bf16 Bsm[BN][BK];

    int tid = threadIdx.x, lane = tid & 63, wid = tid >> 6;
    int sub  = lane >> 3;
    int koff = (lane & 7) * 8;

    const bf16* asrc[4]; const bf16* bsrc[4];
    bf16* adst[4]; bf16* bdst[4];
    const bf16* wdp = wdT + ((size_t)e * DDIM + n0) * HDIM;
#pragma unroll
    for (int i = 0; i < 4; ++i) {
        int c = wid * 4 + i;
        int row = c * 8 + sub;
        int r = m0 + row; if (r > ne - 1) r = ne - 1;   // clamp: finite, never stored
        asrc[i] = hbuf + (size_t)(base + r) * HDIM + koff;
        bsrc[i] = wdp + (size_t)row * HDIM + koff;
        adst[i] = &Asm[c * 8][0];
        bdst[i] = &Bsm[c * 8][0];
    }

    int wr = (wid >> 1) * 64, wc = (wid & 1) * 64;
    f32x4 zero4 = {0.f, 0.f, 0.f, 0.f};
    f32x4 acc[4][4];
#pragma unroll
    for (int mi = 0; mi < 4; ++mi)
#pragma unroll
        for (int ni = 0; ni < 4; ++ni) acc[mi][ni] = zero4;

    for (int k0 = 0; k0 < HDIM; k0 += BK) {
#pragma unroll
        for (int i = 0; i < 4; ++i) gload16(asrc[i] + k0, adst[i]);
#pragma unroll
        for (int i = 0; i < 4; ++i) gload16(bsrc[i] + k0, bdst[i]);
        __syncthreads();
#pragma unroll
        for (int kk = 0; kk < BK; kk += 32) {
            int ko = kk + 8 * (lane >> 4);
            int rl = lane & 15;
            s16x8 a[4], b[4];
#pragma unroll
            for (int mi = 0; mi < 4; ++mi)
                a[mi] = *reinterpret_cast<const s16x8*>(&Asm[wr + mi * 16 + rl][ko]);
#pragma unroll
            for (int ni = 0; ni < 4; ++ni)
                b[ni] = *reinterpret_cast<const s16x8*>(&Bsm[wc + ni * 16 + rl][ko]);
#pragma unroll
            for (int mi = 0; mi < 4; ++mi)
#pragma unroll
                for (int ni = 0; ni < 4; ++ni)
                    acc[mi][ni] = __builtin_amdgcn_mfma_f32_16x16x32_bf16(a[mi], b[ni], acc[mi][ni], 0, 0, 0);
        }
        __syncthreads();
    }

    int rbase = (lane >> 4) * 4, cbase = lane & 15;
#pragma unroll
    for (int mi = 0; mi < 4; ++mi) {
#pragma unroll
        for (int r = 0; r < 4; ++r) {
            int row = m0 + wr + mi * 16 + rbase + r;
            if (row < ne) {
                size_t orow = (size_t)(base + row) * DDIM + n0 + wc + cbase;
#pragma unroll
                for (int ni = 0; ni < 4; ++ni)
                    obuf[orow + ni * 16] = acc[mi][ni][r];
            }
        }
    }
}

// ---------------- combine: y[t] = w0*obuf[slot0] + w1*obuf[slot1] (fixed order) ----------------
__global__ void combine_kernel(const float* __restrict__ obuf, const int* __restrict__ tokslot,
                               const float* __restrict__ r_w, float* __restrict__ y) {
    int i = blockIdx.x * blockDim.x + threadIdx.x;
    int t = i >> 8;            // 256 float4 per token row (D=1024)
    int d4 = (i & 255) * 4;
    float w0 = r_w[2 * t], w1 = r_w[2 * t + 1];
    int s0 = tokslot[2 * t], s1 = tokslot[2 * t + 1];
    float4 a = *reinterpret_cast<const float4*>(obuf + (size_t)s0 * DDIM + d4);
    float4 b = *reinterpret_cast<const float4*>(obuf + (size_t)s1 * DDIM + d4);
    float4 o;
    o.x = w0 * a.x + w1 * b.x;
    o.y = w0 * a.y + w1 * b.y;
    o.z = w0 * a.z + w1 * b.z;
    o.w = w0 * a.w + w1 * b.w;
    *reinterpret_cast<float4*>(y + (size_t)t * DDIM + d4) = o;
}

extern "C" void kernel_launch(void* const* d_in, const int* in_sizes, int n_in,
                              void* d_out, int out_size, void* d_ws, size_t ws_size,
                              hipStream_t stream) {
    const float* x  = (const float*)d_in[0];
    const float* rw = (const float*)d_in[1];
    const float* wg = (const float*)d_in[2];
    const float* wu = (const float*)d_in[3];
    const float* wd = (const float*)d_in[4];
    float* y = (float*)d_out;

    char* ws = (char*)d_ws;
    int*   r_e     = (int*)  (ws + 0);          // 2T ints   = 32768 B
    float* r_w     = (float*)(ws + 32768);      // 2T floats = 32768 B
    int*   cnt     = (int*)  (ws + 65536);      // 8 ints
    int*   cnt2    = (int*)  (ws + 65568);      // 8 ints
    int*   offs    = (int*)  (ws + 65600);      // 9 ints
    int*   list    = (int*)  (ws + 65664);      // 2T ints
    int*   tokslot = (int*)  (ws + 98432);      // 2T ints
    bf16*  xb      = (bf16*) (ws + (1u << 20));             // 8,388,608 B
    bf16*  wgT     = (bf16*) (ws + 9437184ull);             // 33,554,432 B
    bf16*  wuT     = (bf16*) (ws + 42991616ull);            // 33,554,432 B
    bf16*  wdT     = (bf16*) (ws + 76546048ull);            // 33,554,432 B
    bf16*  hbuf    = (bf16*) (ws + 110100480ull);           // 33,554,432 B
    float* obuf    = (float*)(ws + 143654912ull);           // 33,554,432 B  (end ~177.2 MB)

    // weight transposes + casts
    transpose_cast_kernel<<<dim3(DDIM / 64, HDIM / 64, NEXP), 256, 0, stream>>>(wg, wgT, DDIM, HDIM);
    transpose_cast_kernel<<<dim3(DDIM / 64, HDIM / 64, NEXP), 256, 0, stream>>>(wu, wuT, DDIM, HDIM);
    transpose_cast_kernel<<<dim3(HDIM / 64, DDIM / 64, NEXP), 256, 0, stream>>>(wd, wdT, HDIM, DDIM);
    cast_x_kernel<<<dim3(T_TOK * DDIM / 4 / 256), 256, 0, stream>>>(x, xb);

    // routing
    router_kernel<<<dim3(T_TOK / 4), 256, 0, stream>>>(x, rw, r_e, r_w);
    hipMemsetAsync(ws + 65536, 0, 64, stream);  // cnt + cnt2
    count_kernel<<<dim3(2 * T_TOK / 256), 256, 0, stream>>>(r_e, cnt);
    scan_kernel<<<dim3(1), 64, 0, stream>>>(cnt, offs);
    fill_kernel<<<dim3(2 * T_TOK / 256), 256, 0, stream>>>(r_e, offs, cnt2, list, tokslot);

    // expert GEMMs (grouped, worst-case grid with early-exit)
    gateup_kernel<<<dim3(HDIM / BN, T_TOK / BM, NEXP), 256, 0, stream>>>(xb, wgT, wuT, offs, list, hbuf);
    down_kernel<<<dim3(DDIM / BN, T_TOK / BM, NEXP), 256, 0, stream>>>(hbuf, wdT, offs, obuf);

    // combine
    combine_kernel<<<dim3(T_TOK * DDIM / 4 / 256), 256, 0, stream>>>(obuf, tokslot, r_w, y);
}